// Round 1
// baseline (321.882 us; speedup 1.0000x reference)
//
#include <hip/hip_runtime.h>

// LSTM(H=5, in=1), T=2048, B=8192, + ReLU + FC head.
// Round 9: R8 + scalar-matvec rewrite:
//  - v_pk_*_f32 is 2 FMA / 4 cy on SIMD-32 == scalar fma rate, but packed
//    form costs h-splat movs + 2 pk_adds for the split trees. All-scalar
//    matvec: 4 gate rows x 5 serial fma, accumulated straight into the
//    per-gate base (20 insts, 4-way ILP), h0v..h4v consumed directly.
//  - tail fusion: h = fmaf(-wm, Ro, Ro) replaces (1-wm)*Ro (sub+mul -> fma),
//    shortening the structural c2->exp2->fma->rcp->fma tail.
//  - base fmas distributed into the rcp/exp2 latency shadows (i,g after R;
//    f after wm; o after Ro).
// Structure (fixed since R6): 8 lanes/elem, 1024 waves = 1/SIMD, hw exp2/rcp,
// scaled cell state c2 = c*(-2log2e), DPP broadcast of h[0..4].

#define TLEN 2048

__device__ __forceinline__ float fexp2(float v) { return __builtin_amdgcn_exp2f(v); }
__device__ __forceinline__ float frcp(float v)  { return __builtin_amdgcn_rcpf(v); }

template<int CTRL>
__device__ __forceinline__ float dppmov(float v) {
    return __int_as_float(__builtin_amdgcn_mov_dpp(__float_as_int(v), CTRL, 0xF, 0xF, true));
}
template<int CTRL, int BANK_MASK>
__device__ __forceinline__ float dppupd(float old, float v) {
    return __int_as_float(__builtin_amdgcn_update_dpp(
        __float_as_int(old), __float_as_int(v), CTRL, 0xF, BANK_MASK, false));
}

__global__ __launch_bounds__(256, 1) void lstm_fused8t(
    const float* __restrict__ x,      // [B, T, 1]
    const float* __restrict__ W_ih,   // [20, 1]
    const float* __restrict__ W_hh,   // [20, 5]
    const float* __restrict__ b_ih,   // [20]
    const float* __restrict__ b_hh,   // [20]
    const float* __restrict__ W_fc,   // [1, 5]
    const float* __restrict__ b_fc,   // [1]
    float* __restrict__ out, int B)
{
    const int tid = blockIdx.x * 256 + threadIdx.x;
    const int b = tid >> 3;
    const int lane8 = tid & 7;
    const int k = lane8 < 5 ? lane8 : 4;   // owned hidden unit (dup lanes 5-7)

    constexpr float L2E   = 1.4426950408889634f;
    constexpr float P2L2E = 2.8853900817779268f;   // +2*log2e
    constexpr float M2L2E = -2.8853900817779268f;  // -2*log2e

    // Per-lane scalar weights, pre-scaled so exp2 computes e^{-z} / e^{-2z}.
    const int ri = k, rf = 5 + k, rg = 10 + k, ro = 15 + k;
    float wi[5], wf[5], wg[5], wo[5];
#pragma unroll
    for (int m = 0; m < 5; ++m) {
        wi[m] = W_hh[ri * 5 + m] * -L2E;
        wf[m] = W_hh[rf * 5 + m] * -L2E;
        wg[m] = W_hh[rg * 5 + m] * M2L2E;
        wo[m] = W_hh[ro * 5 + m] * -L2E;
    }
    const float wxi = W_ih[ri] * -L2E;
    const float wxf = W_ih[rf] * -L2E;
    const float wxg = W_ih[rg] * M2L2E;
    const float wxo = W_ih[ro] * -L2E;
    const float bci = (b_ih[ri] + b_hh[ri]) * -L2E;
    const float bcf = (b_ih[rf] + b_hh[rf]) * -L2E;
    const float bcg = (b_ih[rg] + b_hh[rg]) * M2L2E;
    const float bco = (b_ih[ro] + b_hh[ro]) * -L2E;

    float c2 = 0.0f;   // scaled cell state: c * (-2*log2e)
    float h0v = 0.0f, h1v = 0.0f, h2v = 0.0f, h3v = 0.0f, h4v = 0.0f;

    const float4* xp = reinterpret_cast<const float4*>(x + (size_t)b * TLEN);
    float4 xa = xp[0], xb = xp[1], xc = xp[2], xd = xp[3];
    // h-independent bases for step 0
    float basei = fmaf(xa.x, wxi, bci);
    float basef = fmaf(xa.x, wxf, bcf);
    float baseg = fmaf(xa.x, wxg, bcg);
    float baseo = fmaf(xa.x, wxo, bco);

#pragma unroll 1
    for (int t16 = 0; t16 < TLEN / 16; ++t16) {
        const int nx = (t16 + 1 < TLEN / 16) ? (t16 + 1) : t16;
        float4 na = xp[4 * nx];
        float4 nb = xp[4 * nx + 1];
        float4 nc = xp[4 * nx + 2];
        float4 nd = xp[4 * nx + 3];
        // NEXT step's x for each of the 16 steps (last is dummy on final iter)
        float xs[16] = {xa.y, xa.z, xa.w, xb.x, xb.y, xb.z, xb.w, xc.x,
                        xc.y, xc.z, xc.w, xd.x, xd.y, xd.z, xd.w, na.x};
#pragma unroll
        for (int q = 0; q < 16; ++q) {
            // Scalar matvec: 4 rows x 5 fma, accumulated into the base.
            // Interleaved rows -> 4 independent chains, dep spacing 8 cy.
            float zi = fmaf(h0v, wi[0], basei);
            float zg = fmaf(h0v, wg[0], baseg);
            float zf = fmaf(h0v, wf[0], basef);
            float zo = fmaf(h0v, wo[0], baseo);
            zi = fmaf(h1v, wi[1], zi);
            zg = fmaf(h1v, wg[1], zg);
            zf = fmaf(h1v, wf[1], zf);
            zo = fmaf(h1v, wo[1], zo);
            zi = fmaf(h2v, wi[2], zi);
            zg = fmaf(h2v, wg[2], zg);
            zf = fmaf(h2v, wf[2], zf);
            zo = fmaf(h2v, wo[2], zo);
            zi = fmaf(h3v, wi[3], zi);
            zg = fmaf(h3v, wg[3], zg);
            zf = fmaf(h3v, wf[3], zf);
            zo = fmaf(h3v, wo[3], zo);
            zi = fmaf(h4v, wi[4], zi);
            zg = fmaf(h4v, wg[4], zg);
            zf = fmaf(h4v, wf[4], zf);
            zo = fmaf(h4v, wo[4], zo);

            const float ui = fexp2(zi);       // e^{-zi}
            const float ug = fexp2(zg);       // e^{-2zg}
            const float uf = fexp2(zf);       // e^{-zf}
            const float uo = fexp2(zo);       // e^{-zo}

            const float Ag = 1.0f + ug;
            const float Af = 1.0f + uf;
            const float Ao = 1.0f + uo;
            const float P  = fmaf(ui, Ag, Ag);   // (1+ui)(1+ug)
            const float D  = P * Af;
            const float R  = frcp(D);

            // next-step bases: fill the rcp/exp2 latency shadows
            const float xn = xs[q];
            basei = fmaf(xn, wxi, bci);
            baseg = fmaf(xn, wxg, bcg);

            const float t2vM = fmaf(ug, P2L2E, M2L2E) * Af;  // (1-ug)*M2L2E*Af
            const float N  = fmaf(P, c2, t2vM);
            c2 = N * R;                                       // scaled cell state
            const float wm = fexp2(c2);                       // e^{-2c}
            basef = fmaf(xn, wxf, bcf);
            const float Den = fmaf(Ao, wm, Ao);               // Ao*(1+wm)
            const float Ro = frcp(Den);
            baseo = fmaf(xn, wxo, bco);
            const float h  = fmaf(-wm, Ro, Ro);               // (1-wm)*Ro = o*tanh(c)

            // DPP broadcast of h[0..4]: 4 independent quad_perm movs first,
            // then the 5 dependent row-shift updates (hazard-friendly order).
            const float t04 = dppmov<0x00>(h);
            const float t1  = dppmov<0x55>(h);
            const float tt2 = dppmov<0xAA>(h);
            const float t3  = dppmov<0xFF>(h);
            h0v = dppupd<0x114, 0xA>(t04, t04);
            h4v = dppupd<0x104, 0x5>(t04, t04);
            h1v = dppupd<0x114, 0xA>(t1, t1);
            h2v = dppupd<0x114, 0xA>(tt2, tt2);
            h3v = dppupd<0x114, 0xA>(t3, t3);
        }
        xa = na; xb = nb; xc = nc; xd = nd;
    }

    if (lane8 == 0) {
        float acc = b_fc[0];
        acc = fmaf(fmaxf(h0v, 0.0f), W_fc[0], acc);
        acc = fmaf(fmaxf(h1v, 0.0f), W_fc[1], acc);
        acc = fmaf(fmaxf(h2v, 0.0f), W_fc[2], acc);
        acc = fmaf(fmaxf(h3v, 0.0f), W_fc[3], acc);
        acc = fmaf(fmaxf(h4v, 0.0f), W_fc[4], acc);
        out[b] = acc;
    }
}

extern "C" void kernel_launch(void* const* d_in, const int* in_sizes, int n_in,
                              void* d_out, int out_size, void* d_ws, size_t ws_size,
                              hipStream_t stream) {
    const float* x    = (const float*)d_in[0];
    const float* W_ih = (const float*)d_in[1];
    const float* W_hh = (const float*)d_in[2];
    const float* b_ih = (const float*)d_in[3];
    const float* b_hh = (const float*)d_in[4];
    const float* W_fc = (const float*)d_in[5];
    const float* b_fc = (const float*)d_in[6];
    float* out = (float*)d_out;
    const int B = out_size;  // 8192
    const int threads = B * 8;  // 65536 = 1024 waves = 1/SIMD
    lstm_fused8t<<<threads / 256, 256, 0, stream>>>(
        x, W_ih, W_hh, b_ih, b_hh, W_fc, b_fc, out, B);
}

// Round 2
// 286.160 us; speedup vs baseline: 1.1248x; 1.1248x over previous
//
#include <hip/hip_runtime.h>

// LSTM(H=5, in=1), T=2048, B=8192, + ReLU + FC head.
// Round 10: revert R9's scalar matvec (regressed +38 cy/step — v_pk_*_f32
// is effectively half issue cost vs scalar fma here, and the 5-deep scalar
// chains added latency on the recurrence cycle). Back to R8's packed
// split-tree matvec, keeping R9's single proven tail win:
//  - h = fmaf(-wm, Ro, Ro) replaces (1-wm)*Ro: -1 instr issue, -4 cy on the
//    serial c2->exp2->fma->rcp->h->DPP tail.
// Structure (fixed since R6): 8 lanes/elem, 1024 waves = 1/SIMD, hw exp2/rcp,
// packed (i,g)/(f,o) matvec, scaled cell state c2=c*(-2log2e), DPP broadcast,
// hazard-aware ordering (base fmas in rcp shadows; base13 covers h->DPP).

#define TLEN 2048

typedef float v2f __attribute__((ext_vector_type(2)));

__device__ __forceinline__ float fexp2(float v) { return __builtin_amdgcn_exp2f(v); }
__device__ __forceinline__ float frcp(float v)  { return __builtin_amdgcn_rcpf(v); }
__device__ __forceinline__ v2f fma2(v2f a, v2f b, v2f c) {
    return __builtin_elementwise_fma(a, b, c);
}

template<int CTRL>
__device__ __forceinline__ float dppmov(float v) {
    return __int_as_float(__builtin_amdgcn_mov_dpp(__float_as_int(v), CTRL, 0xF, 0xF, true));
}
template<int CTRL, int BANK_MASK>
__device__ __forceinline__ float dppupd(float old, float v) {
    return __int_as_float(__builtin_amdgcn_update_dpp(
        __float_as_int(old), __float_as_int(v), CTRL, 0xF, BANK_MASK, false));
}

__global__ __launch_bounds__(256, 1) void lstm_fused8t(
    const float* __restrict__ x,      // [B, T, 1]
    const float* __restrict__ W_ih,   // [20, 1]
    const float* __restrict__ W_hh,   // [20, 5]
    const float* __restrict__ b_ih,   // [20]
    const float* __restrict__ b_hh,   // [20]
    const float* __restrict__ W_fc,   // [1, 5]
    const float* __restrict__ b_fc,   // [1]
    float* __restrict__ out, int B)
{
    const int tid = blockIdx.x * 256 + threadIdx.x;
    const int b = tid >> 3;
    const int lane8 = tid & 7;
    const int k = lane8 < 5 ? lane8 : 4;   // owned hidden unit (dup lanes 5-7)

    constexpr float L2E   = 1.4426950408889634f;
    constexpr float P2L2E = 2.8853900817779268f;   // +2*log2e
    constexpr float M2L2E = -2.8853900817779268f;  // -2*log2e

    // Packed per-lane weights: pair02 = (i-row, g-row), pair13 = (f-row, o-row)
    v2f wih02, wih13, bias02, bias13, whh02[5], whh13[5];
    {
        const int ri = k, rf = 5 + k, rg = 10 + k, ro = 15 + k;
        wih02  = v2f{W_ih[ri] * -L2E,               W_ih[rg] * M2L2E};
        wih13  = v2f{W_ih[rf] * -L2E,               W_ih[ro] * -L2E};
        bias02 = v2f{(b_ih[ri] + b_hh[ri]) * -L2E,  (b_ih[rg] + b_hh[rg]) * M2L2E};
        bias13 = v2f{(b_ih[rf] + b_hh[rf]) * -L2E,  (b_ih[ro] + b_hh[ro]) * -L2E};
#pragma unroll
        for (int m = 0; m < 5; ++m) {
            whh02[m] = v2f{W_hh[ri * 5 + m] * -L2E,  W_hh[rg * 5 + m] * M2L2E};
            whh13[m] = v2f{W_hh[rf * 5 + m] * -L2E,  W_hh[ro * 5 + m] * -L2E};
        }
    }

    float c2 = 0.0f;   // scaled cell state: c * (-2*log2e)
    float h0v = 0.0f, h1v = 0.0f, h2v = 0.0f, h3v = 0.0f, h4v = 0.0f;

    const float4* xp = reinterpret_cast<const float4*>(x + (size_t)b * TLEN);
    float4 xa = xp[0], xb = xp[1], xc = xp[2], xd = xp[3];
    // h-independent base for step 0
    v2f base02 = fma2(v2f{xa.x, xa.x}, wih02, bias02);
    v2f base13 = fma2(v2f{xa.x, xa.x}, wih13, bias13);

#pragma unroll 1
    for (int t16 = 0; t16 < TLEN / 16; ++t16) {
        const int nx = (t16 + 1 < TLEN / 16) ? (t16 + 1) : t16;
        float4 na = xp[4 * nx];
        float4 nb = xp[4 * nx + 1];
        float4 nc = xp[4 * nx + 2];
        float4 nd = xp[4 * nx + 3];
        // NEXT step's x for each of the 16 steps (last is dummy on final iter)
        float xs[16] = {xa.y, xa.z, xa.w, xb.x, xb.y, xb.z, xb.w, xc.x,
                        xc.y, xc.z, xc.w, xd.x, xd.y, xd.z, xd.w, na.x};
#pragma unroll
        for (int q = 0; q < 16; ++q) {
            const v2f h0s = v2f{h0v, h0v}, h1s = v2f{h1v, h1v}, h2s = v2f{h2v, h2v};
            const v2f h3s = v2f{h3v, h3v}, h4s = v2f{h4v, h4v};

            // z pairs from precomputed base (split-accumulated trees)
            v2f za02 = fma2(h0s, whh02[0], base02);
            za02 = fma2(h1s, whh02[1], za02);
            v2f zb02 = fma2(h3s, whh02[3], h2s * whh02[2]);
            zb02 = fma2(h4s, whh02[4], zb02);
            const v2f z02 = za02 + zb02;         // (zi*-L2E, zg*-2L2E)

            v2f za13 = fma2(h0s, whh13[0], base13);
            za13 = fma2(h1s, whh13[1], za13);
            v2f zb13 = fma2(h3s, whh13[3], h2s * whh13[2]);
            zb13 = fma2(h4s, whh13[4], zb13);
            const v2f z13 = za13 + zb13;         // (zf*-L2E, zo*-L2E)

            const float ui = fexp2(z02.x);       // e^{-zi}
            const float ug = fexp2(z02.y);       // e^{-2zg}
            const float uf = fexp2(z13.x);       // e^{-zf}
            const float uo = fexp2(z13.y);       // e^{-zo}

            const float Ag = 1.0f + ug;
            const float Af = 1.0f + uf;
            const float Ao = 1.0f + uo;
            const float P  = fmaf(ui, Ag, Ag);   // (1+ui)(1+ug)
            const float D  = P * Af;
            const float R  = frcp(D);

            // first half of next-step base: fills rcp latency
            const float xn = xs[q];
            base02 = fma2(v2f{xn, xn}, wih02, bias02);

            const float t2vM = fmaf(ug, P2L2E, M2L2E) * Af;  // (1-ug)*M2L2E*Af
            const float N  = fmaf(P, c2, t2vM);
            c2 = N * R;                                       // scaled cell state
            const float wm = fexp2(c2);                       // e^{-2c}
            const float Den = fmaf(Ao, wm, Ao);               // Ao*(1+wm)
            const float Ro = frcp(Den);
            const float h  = fmaf(-wm, Ro, Ro);               // (1-wm)*Ro = o*tanh(c)

            // second half of next-step base: covers the h->DPP hazard window
            base13 = fma2(v2f{xn, xn}, wih13, bias13);

            // DPP broadcast of h[0..4]: 4 independent quad_perm movs first,
            // then the 5 dependent row-shift updates (hazard-friendly order).
            const float t04 = dppmov<0x00>(h);
            const float t1  = dppmov<0x55>(h);
            const float tt2 = dppmov<0xAA>(h);
            const float t3  = dppmov<0xFF>(h);
            h0v = dppupd<0x114, 0xA>(t04, t04);
            h4v = dppupd<0x104, 0x5>(t04, t04);
            h1v = dppupd<0x114, 0xA>(t1, t1);
            h2v = dppupd<0x114, 0xA>(tt2, tt2);
            h3v = dppupd<0x114, 0xA>(t3, t3);
        }
        xa = na; xb = nb; xc = nc; xd = nd;
    }

    if (lane8 == 0) {
        float acc = b_fc[0];
        acc = fmaf(fmaxf(h0v, 0.0f), W_fc[0], acc);
        acc = fmaf(fmaxf(h1v, 0.0f), W_fc[1], acc);
        acc = fmaf(fmaxf(h2v, 0.0f), W_fc[2], acc);
        acc = fmaf(fmaxf(h3v, 0.0f), W_fc[3], acc);
        acc = fmaf(fmaxf(h4v, 0.0f), W_fc[4], acc);
        out[b] = acc;
    }
}

extern "C" void kernel_launch(void* const* d_in, const int* in_sizes, int n_in,
                              void* d_out, int out_size, void* d_ws, size_t ws_size,
                              hipStream_t stream) {
    const float* x    = (const float*)d_in[0];
    const float* W_ih = (const float*)d_in[1];
    const float* W_hh = (const float*)d_in[2];
    const float* b_ih = (const float*)d_in[3];
    const float* b_hh = (const float*)d_in[4];
    const float* W_fc = (const float*)d_in[5];
    const float* b_fc = (const float*)d_in[6];
    float* out = (float*)d_out;
    const int B = out_size;  // 8192
    const int threads = B * 8;  // 65536 = 1024 waves = 1/SIMD
    lstm_fused8t<<<threads / 256, 256, 0, stream>>>(
        x, W_ih, W_hh, b_ih, b_hh, W_fc, b_fc, out, B);
}

// Round 3
// 272.250 us; speedup vs baseline: 1.1823x; 1.0511x over previous
//
#include <hip/hip_runtime.h>

// LSTM(H=5, in=1), T=2048, B=8192, + ReLU + FC head.
// Round 11: R10 + two surgical issue cuts (both bitwise-preserving):
//  - dup-lane remap: lanes 5-7 duplicate units 1-3 (not unit 4), so the
//    upper quad holds {h4,h1,h2,h3}. quad_perm(m) then broadcasts h_m to
//    BOTH quads in ONE DPP for m=1,2,3. Broadcast: 9 DPP ops -> 6, and
//    h1v/h2v/h3v arrive one DPP earlier on the recurrence path.
//  - outer-loop unroll-2 ping-pong (xa..xd / ya..yd): kills the 16
//    v_mov register-copy per 16-step block + halves branch overhead.
// Model: ~267 cy/step = trans 112 (5 exp2 + 2 rcp, algebraic minimum) +
// pk 56 + scalar 22 + DPP 18 + ~60 serial-tail stall. This round: -8cy.
// Structure (fixed since R6): 8 lanes/elem, 1024 waves = 1/SIMD, hw
// exp2/rcp, packed (i,g)/(f,o) matvec, scaled cell state c2=c*(-2log2e).

#define TLEN 2048

typedef float v2f __attribute__((ext_vector_type(2)));

__device__ __forceinline__ float fexp2(float v) { return __builtin_amdgcn_exp2f(v); }
__device__ __forceinline__ float frcp(float v)  { return __builtin_amdgcn_rcpf(v); }
__device__ __forceinline__ v2f fma2(v2f a, v2f b, v2f c) {
    return __builtin_elementwise_fma(a, b, c);
}

template<int CTRL>
__device__ __forceinline__ float dppmov(float v) {
    return __int_as_float(__builtin_amdgcn_mov_dpp(__float_as_int(v), CTRL, 0xF, 0xF, true));
}
template<int CTRL, int BANK_MASK>
__device__ __forceinline__ float dppupd(float old, float v) {
    return __int_as_float(__builtin_amdgcn_update_dpp(
        __float_as_int(old), __float_as_int(v), CTRL, 0xF, BANK_MASK, false));
}

__global__ __launch_bounds__(256, 1) void lstm_fused8t(
    const float* __restrict__ x,      // [B, T, 1]
    const float* __restrict__ W_ih,   // [20, 1]
    const float* __restrict__ W_hh,   // [20, 5]
    const float* __restrict__ b_ih,   // [20]
    const float* __restrict__ b_hh,   // [20]
    const float* __restrict__ W_fc,   // [1, 5]
    const float* __restrict__ b_fc,   // [1]
    float* __restrict__ out, int B)
{
    const int tid = blockIdx.x * 256 + threadIdx.x;
    const int b = tid >> 3;
    const int lane8 = tid & 7;
    // Lanes 5-7 duplicate units 1-3 so the upper quad holds {h4,h1,h2,h3}:
    // quad_perm(m) broadcasts h_m to both quads in one DPP for m=1,2,3.
    const int k = lane8 < 5 ? lane8 : lane8 - 4;

    constexpr float L2E   = 1.4426950408889634f;
    constexpr float P2L2E = 2.8853900817779268f;   // +2*log2e
    constexpr float M2L2E = -2.8853900817779268f;  // -2*log2e

    // Packed per-lane weights: pair02 = (i-row, g-row), pair13 = (f-row, o-row)
    v2f wih02, wih13, bias02, bias13, whh02[5], whh13[5];
    {
        const int ri = k, rf = 5 + k, rg = 10 + k, ro = 15 + k;
        wih02  = v2f{W_ih[ri] * -L2E,               W_ih[rg] * M2L2E};
        wih13  = v2f{W_ih[rf] * -L2E,               W_ih[ro] * -L2E};
        bias02 = v2f{(b_ih[ri] + b_hh[ri]) * -L2E,  (b_ih[rg] + b_hh[rg]) * M2L2E};
        bias13 = v2f{(b_ih[rf] + b_hh[rf]) * -L2E,  (b_ih[ro] + b_hh[ro]) * -L2E};
#pragma unroll
        for (int m = 0; m < 5; ++m) {
            whh02[m] = v2f{W_hh[ri * 5 + m] * -L2E,  W_hh[rg * 5 + m] * M2L2E};
            whh13[m] = v2f{W_hh[rf * 5 + m] * -L2E,  W_hh[ro * 5 + m] * -L2E};
        }
    }

    float c2 = 0.0f;   // scaled cell state: c * (-2*log2e)
    float h0v = 0.0f, h1v = 0.0f, h2v = 0.0f, h3v = 0.0f, h4v = 0.0f;

    const float4* xp = reinterpret_cast<const float4*>(x + (size_t)b * TLEN);
    float4 xa = xp[0], xb = xp[1], xc = xp[2], xd = xp[3];
    // h-independent base for step 0
    v2f base02 = fma2(v2f{xa.x, xa.x}, wih02, bias02);
    v2f base13 = fma2(v2f{xa.x, xa.x}, wih13, bias13);

    // 16-step body: S0..S3 = this half's four float4s, NEXT0 = next block's
    // first x (feeds the base for the step after this block's last).
#define STEP16(S0, S1, S2, S3, NEXT0) do {                                    \
    float xs[16] = {S0.y, S0.z, S0.w, S1.x, S1.y, S1.z, S1.w, S2.x,           \
                    S2.y, S2.z, S2.w, S3.x, S3.y, S3.z, S3.w, (NEXT0)};       \
    _Pragma("unroll")                                                         \
    for (int q = 0; q < 16; ++q) {                                            \
        const v2f h0s = v2f{h0v, h0v}, h1s = v2f{h1v, h1v}, h2s = v2f{h2v, h2v}; \
        const v2f h3s = v2f{h3v, h3v}, h4s = v2f{h4v, h4v};                   \
        v2f za02 = fma2(h0s, whh02[0], base02);                               \
        za02 = fma2(h1s, whh02[1], za02);                                     \
        v2f zb02 = fma2(h3s, whh02[3], h2s * whh02[2]);                       \
        zb02 = fma2(h4s, whh02[4], zb02);                                     \
        const v2f z02 = za02 + zb02;         /* (zi*-L2E, zg*-2L2E) */        \
        v2f za13 = fma2(h0s, whh13[0], base13);                               \
        za13 = fma2(h1s, whh13[1], za13);                                     \
        v2f zb13 = fma2(h3s, whh13[3], h2s * whh13[2]);                       \
        zb13 = fma2(h4s, whh13[4], zb13);                                     \
        const v2f z13 = za13 + zb13;         /* (zf*-L2E, zo*-L2E) */         \
        const float ui = fexp2(z02.x);       /* e^{-zi}  */                   \
        const float ug = fexp2(z02.y);       /* e^{-2zg} */                   \
        const float uf = fexp2(z13.x);       /* e^{-zf}  */                   \
        const float uo = fexp2(z13.y);       /* e^{-zo}  */                   \
        const float Ag = 1.0f + ug;                                           \
        const float Af = 1.0f + uf;                                           \
        const float Ao = 1.0f + uo;                                           \
        const float P  = fmaf(ui, Ag, Ag);   /* (1+ui)(1+ug) */               \
        const float D  = P * Af;                                              \
        const float R  = frcp(D);                                             \
        const float xn = xs[q];                                               \
        base02 = fma2(v2f{xn, xn}, wih02, bias02);                            \
        const float t2vM = fmaf(ug, P2L2E, M2L2E) * Af;  /* (1-ug)*M2L2E*Af */\
        const float N  = fmaf(P, c2, t2vM);                                   \
        c2 = N * R;                          /* scaled cell state */          \
        const float wm = fexp2(c2);          /* e^{-2c} */                    \
        const float Den = fmaf(Ao, wm, Ao);  /* Ao*(1+wm) */                  \
        const float Ro = frcp(Den);                                           \
        const float h  = fmaf(-wm, Ro, Ro);  /* (1-wm)*Ro = o*tanh(c) */      \
        base13 = fma2(v2f{xn, xn}, wih13, bias13);                            \
        /* 6-op DPP broadcast: t04 mov first, 3 independent single-mov       */\
        /* broadcasts fill its hazard window, then the 2 dependent updates.  */\
        const float t04 = dppmov<0x00>(h);   /* lower=h0, upper=h4 */         \
        h1v = dppmov<0x55>(h);               /* both quads <- h1 */           \
        h2v = dppmov<0xAA>(h);               /* both quads <- h2 */           \
        h3v = dppmov<0xFF>(h);               /* both quads <- h3 */           \
        h0v = dppupd<0x114, 0xA>(t04, t04);  /* row_shl:4, upper <- h0 */     \
        h4v = dppupd<0x104, 0x5>(t04, t04);  /* row_shr:4, lower <- h4 */     \
    } } while (0)

#pragma unroll 1
    for (int t32 = 0; t32 < TLEN / 32; ++t32) {
        // half A: consume xa..xd; prefetch B-set (always in range)
        const int ib = 8 * t32 + 4;
        float4 ya = xp[ib], yb = xp[ib + 1], yc = xp[ib + 2], yd = xp[ib + 3];
        STEP16(xa, xb, xc, xd, ya.x);
        // half B: consume ya..yd; prefetch next A-set (clamped dummy at end)
        const int ia = (t32 + 1 < TLEN / 32) ? 8 * t32 + 8 : 0;
        xa = xp[ia]; xb = xp[ia + 1]; xc = xp[ia + 2]; xd = xp[ia + 3];
        STEP16(ya, yb, yc, yd, xa.x);
    }
#undef STEP16

    if (lane8 == 0) {
        float acc = b_fc[0];
        acc = fmaf(fmaxf(h0v, 0.0f), W_fc[0], acc);
        acc = fmaf(fmaxf(h1v, 0.0f), W_fc[1], acc);
        acc = fmaf(fmaxf(h2v, 0.0f), W_fc[2], acc);
        acc = fmaf(fmaxf(h3v, 0.0f), W_fc[3], acc);
        acc = fmaf(fmaxf(h4v, 0.0f), W_fc[4], acc);
        out[b] = acc;
    }
}

extern "C" void kernel_launch(void* const* d_in, const int* in_sizes, int n_in,
                              void* d_out, int out_size, void* d_ws, size_t ws_size,
                              hipStream_t stream) {
    const float* x    = (const float*)d_in[0];
    const float* W_ih = (const float*)d_in[1];
    const float* W_hh = (const float*)d_in[2];
    const float* b_ih = (const float*)d_in[3];
    const float* b_hh = (const float*)d_in[4];
    const float* W_fc = (const float*)d_in[5];
    const float* b_fc = (const float*)d_in[6];
    float* out = (float*)d_out;
    const int B = out_size;  // 8192
    const int threads = B * 8;  // 65536 = 1024 waves = 1/SIMD
    lstm_fused8t<<<threads / 256, 256, 0, stream>>>(
        x, W_ih, W_hh, b_ih, b_hh, W_fc, b_fc, out, B);
}

// Round 4
// 272.173 us; speedup vs baseline: 1.1826x; 1.0003x over previous
//
#include <hip/hip_runtime.h>

// LSTM(H=5, in=1), T=2048, B=8192, + ReLU + FC head.
// Round 12: R11 + recurrence-latency ordering (compiler can't reorder FP
// sums without fast-math, so source order = schedule):
//  - z-trees root at h1 (first DPP to complete); h0 (last-arriving, 2-op
//    DPP chain) demoted to depth-2 of tree1. h4 stays at tree2's end.
//  - DPP order: h1v mov first (feeds tree root ASAP), t04 second, h2v/h3v
//    fill t04's DPP-after-DPP hazard window, dependent updates last.
// Model: 249 cy/step = 202 issue (12pk*4 + 2base*4 + 7trans*16 + 11sc*2 +
// 6dpp*2) + 47 tail stall; trans=16cy confirmed by VALUBusy=80%=202/249.
// Trans count, lane layout, 6-op trees, 6-op DPP all at structural floor.
// Structure (fixed since R6): 8 lanes/elem, 1024 waves = 1/SIMD, hw
// exp2/rcp, packed (i,g)/(f,o) matvec, scaled cell state c2=c*(-2log2e).

#define TLEN 2048

typedef float v2f __attribute__((ext_vector_type(2)));

__device__ __forceinline__ float fexp2(float v) { return __builtin_amdgcn_exp2f(v); }
__device__ __forceinline__ float frcp(float v)  { return __builtin_amdgcn_rcpf(v); }
__device__ __forceinline__ v2f fma2(v2f a, v2f b, v2f c) {
    return __builtin_elementwise_fma(a, b, c);
}

template<int CTRL>
__device__ __forceinline__ float dppmov(float v) {
    return __int_as_float(__builtin_amdgcn_mov_dpp(__float_as_int(v), CTRL, 0xF, 0xF, true));
}
template<int CTRL, int BANK_MASK>
__device__ __forceinline__ float dppupd(float old, float v) {
    return __int_as_float(__builtin_amdgcn_update_dpp(
        __float_as_int(old), __float_as_int(v), CTRL, 0xF, BANK_MASK, false));
}

__global__ __launch_bounds__(256, 1) void lstm_fused8t(
    const float* __restrict__ x,      // [B, T, 1]
    const float* __restrict__ W_ih,   // [20, 1]
    const float* __restrict__ W_hh,   // [20, 5]
    const float* __restrict__ b_ih,   // [20]
    const float* __restrict__ b_hh,   // [20]
    const float* __restrict__ W_fc,   // [1, 5]
    const float* __restrict__ b_fc,   // [1]
    float* __restrict__ out, int B)
{
    const int tid = blockIdx.x * 256 + threadIdx.x;
    const int b = tid >> 3;
    const int lane8 = tid & 7;
    // Lanes 5-7 duplicate units 1-3 so the upper quad holds {h4,h1,h2,h3}:
    // quad_perm(m) broadcasts h_m to both quads in one DPP for m=1,2,3.
    const int k = lane8 < 5 ? lane8 : lane8 - 4;

    constexpr float L2E   = 1.4426950408889634f;
    constexpr float P2L2E = 2.8853900817779268f;   // +2*log2e
    constexpr float M2L2E = -2.8853900817779268f;  // -2*log2e

    // Packed per-lane weights: pair02 = (i-row, g-row), pair13 = (f-row, o-row)
    v2f wih02, wih13, bias02, bias13, whh02[5], whh13[5];
    {
        const int ri = k, rf = 5 + k, rg = 10 + k, ro = 15 + k;
        wih02  = v2f{W_ih[ri] * -L2E,               W_ih[rg] * M2L2E};
        wih13  = v2f{W_ih[rf] * -L2E,               W_ih[ro] * -L2E};
        bias02 = v2f{(b_ih[ri] + b_hh[ri]) * -L2E,  (b_ih[rg] + b_hh[rg]) * M2L2E};
        bias13 = v2f{(b_ih[rf] + b_hh[rf]) * -L2E,  (b_ih[ro] + b_hh[ro]) * -L2E};
#pragma unroll
        for (int m = 0; m < 5; ++m) {
            whh02[m] = v2f{W_hh[ri * 5 + m] * -L2E,  W_hh[rg * 5 + m] * M2L2E};
            whh13[m] = v2f{W_hh[rf * 5 + m] * -L2E,  W_hh[ro * 5 + m] * -L2E};
        }
    }

    float c2 = 0.0f;   // scaled cell state: c * (-2*log2e)
    float h0v = 0.0f, h1v = 0.0f, h2v = 0.0f, h3v = 0.0f, h4v = 0.0f;

    const float4* xp = reinterpret_cast<const float4*>(x + (size_t)b * TLEN);
    float4 xa = xp[0], xb = xp[1], xc = xp[2], xd = xp[3];
    // h-independent base for step 0
    v2f base02 = fma2(v2f{xa.x, xa.x}, wih02, bias02);
    v2f base13 = fma2(v2f{xa.x, xa.x}, wih13, bias13);

    // 16-step body: S0..S3 = this half's four float4s, NEXT0 = next block's
    // first x (feeds the base for the step after this block's last).
    // Tree order: root at h1 (earliest DPP), h0 (latest) at depth-2.
#define STEP16(S0, S1, S2, S3, NEXT0) do {                                    \
    float xs[16] = {S0.y, S0.z, S0.w, S1.x, S1.y, S1.z, S1.w, S2.x,           \
                    S2.y, S2.z, S2.w, S3.x, S3.y, S3.z, S3.w, (NEXT0)};       \
    _Pragma("unroll")                                                         \
    for (int q = 0; q < 16; ++q) {                                            \
        const v2f h0s = v2f{h0v, h0v}, h1s = v2f{h1v, h1v}, h2s = v2f{h2v, h2v}; \
        const v2f h3s = v2f{h3v, h3v}, h4s = v2f{h4v, h4v};                   \
        v2f za02 = fma2(h1s, whh02[1], base02);                               \
        za02 = fma2(h0s, whh02[0], za02);                                     \
        v2f zb02 = fma2(h3s, whh02[3], h2s * whh02[2]);                       \
        zb02 = fma2(h4s, whh02[4], zb02);                                     \
        const v2f z02 = za02 + zb02;         /* (zi*-L2E, zg*-2L2E) */        \
        v2f za13 = fma2(h1s, whh13[1], base13);                               \
        za13 = fma2(h0s, whh13[0], za13);                                     \
        v2f zb13 = fma2(h3s, whh13[3], h2s * whh13[2]);                       \
        zb13 = fma2(h4s, whh13[4], zb13);                                     \
        const v2f z13 = za13 + zb13;         /* (zf*-L2E, zo*-L2E) */         \
        const float ui = fexp2(z02.x);       /* e^{-zi}  */                   \
        const float ug = fexp2(z02.y);       /* e^{-2zg} */                   \
        const float uf = fexp2(z13.x);       /* e^{-zf}  */                   \
        const float uo = fexp2(z13.y);       /* e^{-zo}  */                   \
        const float Ag = 1.0f + ug;                                           \
        const float Af = 1.0f + uf;                                           \
        const float Ao = 1.0f + uo;                                           \
        const float P  = fmaf(ui, Ag, Ag);   /* (1+ui)(1+ug) */               \
        const float D  = P * Af;                                              \
        const float R  = frcp(D);                                             \
        const float xn = xs[q];                                               \
        base02 = fma2(v2f{xn, xn}, wih02, bias02);                            \
        const float t2vM = fmaf(ug, P2L2E, M2L2E) * Af;  /* (1-ug)*M2L2E*Af */\
        const float N  = fmaf(P, c2, t2vM);                                   \
        c2 = N * R;                          /* scaled cell state */          \
        const float wm = fexp2(c2);          /* e^{-2c} */                    \
        const float Den = fmaf(Ao, wm, Ao);  /* Ao*(1+wm) */                  \
        const float Ro = frcp(Den);                                           \
        const float h  = fmaf(-wm, Ro, Ro);  /* (1-wm)*Ro = o*tanh(c) */      \
        base13 = fma2(v2f{xn, xn}, wih13, bias13);                            \
        /* DPP order: h1v first (feeds tree roots ASAP), t04 second,         */\
        /* h2v/h3v fill t04's hazard window, dependent updates last.         */\
        h1v = dppmov<0x55>(h);               /* both quads <- h1 */           \
        const float t04 = dppmov<0x00>(h);   /* lower=h0, upper=h4 */         \
        h2v = dppmov<0xAA>(h);               /* both quads <- h2 */           \
        h3v = dppmov<0xFF>(h);               /* both quads <- h3 */           \
        h0v = dppupd<0x114, 0xA>(t04, t04);  /* row_shl:4, upper <- h0 */     \
        h4v = dppupd<0x104, 0x5>(t04, t04);  /* row_shr:4, lower <- h4 */     \
    } } while (0)

#pragma unroll 1
    for (int t32 = 0; t32 < TLEN / 32; ++t32) {
        // half A: consume xa..xd; prefetch B-set (always in range)
        const int ib = 8 * t32 + 4;
        float4 ya = xp[ib], yb = xp[ib + 1], yc = xp[ib + 2], yd = xp[ib + 3];
        STEP16(xa, xb, xc, xd, ya.x);
        // half B: consume ya..yd; prefetch next A-set (clamped dummy at end)
        const int ia = (t32 + 1 < TLEN / 32) ? 8 * t32 + 8 : 0;
        xa = xp[ia]; xb = xp[ia + 1]; xc = xp[ia + 2]; xd = xp[ia + 3];
        STEP16(ya, yb, yc, yd, xa.x);
    }
#undef STEP16

    if (lane8 == 0) {
        float acc = b_fc[0];
        acc = fmaf(fmaxf(h0v, 0.0f), W_fc[0], acc);
        acc = fmaf(fmaxf(h1v, 0.0f), W_fc[1], acc);
        acc = fmaf(fmaxf(h2v, 0.0f), W_fc[2], acc);
        acc = fmaf(fmaxf(h3v, 0.0f), W_fc[3], acc);
        acc = fmaf(fmaxf(h4v, 0.0f), W_fc[4], acc);
        out[b] = acc;
    }
}

extern "C" void kernel_launch(void* const* d_in, const int* in_sizes, int n_in,
                              void* d_out, int out_size, void* d_ws, size_t ws_size,
                              hipStream_t stream) {
    const float* x    = (const float*)d_in[0];
    const float* W_ih = (const float*)d_in[1];
    const float* W_hh = (const float*)d_in[2];
    const float* b_ih = (const float*)d_in[3];
    const float* b_hh = (const float*)d_in[4];
    const float* W_fc = (const float*)d_in[5];
    const float* b_fc = (const float*)d_in[6];
    float* out = (float*)d_out;
    const int B = out_size;  // 8192
    const int threads = B * 8;  // 65536 = 1024 waves = 1/SIMD
    lstm_fused8t<<<threads / 256, 256, 0, stream>>>(
        x, W_ih, W_hh, b_ih, b_hh, W_fc, b_fc, out, B);
}